// Round 1
// baseline (2207.758 us; speedup 1.0000x reference)
//
#include <hip/hip_runtime.h>
#include <stdint.h>
#include <stddef.h>

// Problem constants (fixed by the reference)
#define M_ROWS 32768      // B*N = 16*2048
#define N_CODES 8192
#define K_DIM 512
#define BM 128
#define BN 128
#define BK 32
#define CAND_CAP (4u*1024u*1024u)
#define TAU2 2.0f         // 2*tau admission margin for bf16 approx distances (>10 sigma)

// Output layout (floats): z_q [0,16777216), codes [16777216,16809984), loss, perp
#define OFF_CODES 16777216
#define OFF_LOSS  (16777216 + 32768)
#define OFF_PERP  (16777216 + 32768 + 1)

using short8  = __attribute__((ext_vector_type(8))) short;
using ushort8 = __attribute__((ext_vector_type(8))) unsigned short;
using f32x4   = __attribute__((ext_vector_type(4))) float;

typedef unsigned short u16;
typedef unsigned int   u32;
typedef unsigned long long u64;

// ---- orderable-uint encoding of float (monotone: uint min == float min) ----
__device__ __forceinline__ u32 ford(float f) {
    u32 u = __float_as_uint(f);
    return (u & 0x80000000u) ? ~u : (u | 0x80000000u);
}
__device__ __forceinline__ float fordinv(u32 u) {
    u32 v = (u & 0x80000000u) ? (u & 0x7FFFFFFFu) : ~u;
    return __uint_as_float(v);
}
// fp32 -> bf16 (RNE)
__device__ __forceinline__ u16 f2bf(float f) {
    u32 u = __float_as_uint(f);
    u = u + 0x7FFFu + ((u >> 16) & 1u);
    return (u16)(u >> 16);
}

// async global->LDS, 16B per lane; LDS dest = wave-uniform base + lane*16
__device__ __forceinline__ void ldg_to_lds16(const u16* g, u16* l) {
    __builtin_amdgcn_global_load_lds((__attribute__((address_space(1))) void*)(g),
                                     (__attribute__((address_space(3))) void*)(l),
                                     16, 0, 0);
}

// ---------------- init scratch state ----------------
__global__ void k_init(u32* rowMin, u64* rowBest, u32* counts, u32* candCnt) {
    int i = blockIdx.x * blockDim.x + threadIdx.x;
    if (i < M_ROWS) { rowMin[i] = 0xFFFFFFFFu; rowBest[i] = ~0ull; }
    if (i < N_CODES) counts[i] = 0u;
    if (i == 0) *candCnt = 0u;
}

// ------------- fp32 -> bf16 convert + row squared norms -------------
// block = 256 threads = 4 waves, one row per wave (rows have 512 elems; 8/lane)
__global__ void k_convert(const float* __restrict__ src, u16* __restrict__ dst,
                          float* __restrict__ nrm2, int nrows) {
    int row  = blockIdx.x * 4 + (threadIdx.x >> 6);
    int lane = threadIdx.x & 63;
    if (row >= nrows) return;
    const float* p = src + (size_t)row * K_DIM + lane * 8;
    float4 a = *(const float4*)p;
    float4 b = *(const float4*)(p + 4);
    ushort8 v;
    v[0]=f2bf(a.x); v[1]=f2bf(a.y); v[2]=f2bf(a.z); v[3]=f2bf(a.w);
    v[4]=f2bf(b.x); v[5]=f2bf(b.y); v[6]=f2bf(b.z); v[7]=f2bf(b.w);
    *(ushort8*)(dst + (size_t)row * K_DIM + lane * 8) = v;
    float ss = a.x*a.x + a.y*a.y + a.z*a.z + a.w*a.w
             + b.x*b.x + b.y*b.y + b.z*b.z + b.w*b.w;
    #pragma unroll
    for (int s = 32; s; s >>= 1) ss += __shfl_xor(ss, s);
    if (lane == 0) nrm2[row] = ss;
}

// ---------------- main bf16 GEMM + fused min/candidate epilogue ----------------
// C[m,n] = sum_k zb[m,k]*eb[n,k];  s = en2[n] - 2*C  (row-wise argmin target)
// grid: x = row-stripe (256), y = code-chunk (64). 256 threads = 4 waves,
// each wave computes a 64x64 quadrant as 4x4 MFMA 16x16x32 frags.
// LDS tiles are XOR-swizzled at 16B-block granularity:
//   block (R,g), g=k-group 0..3, stored at slot R*4 + (g ^ ((R>>2)&3))
// -> ds_read_b128 frag reads are 2-way (free) instead of 8-way conflicted,
//    and global_load_lds (no padding allowed) still works.
__global__ __launch_bounds__(256, 2)
void k_gemm(const u16* __restrict__ zb, const u16* __restrict__ eb,
            const float* __restrict__ en2, u32* __restrict__ rowMin,
            u32* __restrict__ candCnt, u32* __restrict__ cand) {
    __shared__ __align__(16) u16 As[BM * BK];
    __shared__ __align__(16) u16 Bs[BN * BK];
    __shared__ float en2s[BN];
    __shared__ u32 threshL[BM];

    const int tid  = threadIdx.x;
    const int lane = tid & 63;
    const int wave = tid >> 6;
    const int rowTile = blockIdx.x * BM;
    const int nTile   = blockIdx.y * BN;
    const int wm = (wave >> 1) * 64;   // wave's row quadrant
    const int wn = (wave & 1) * 64;    // wave's col quadrant

    if (tid < BN) { en2s[tid] = en2[nTile + tid]; threshL[tid] = 0xFFFFFFFFu; }

    // staging addresses: each wave issues 2 chunks of A and 2 of B per K-iter.
    // chunk c covers tile rows [c*16, c*16+16); lane l -> row c*16 + (l>>2),
    // k-group g = (l&3) ^ ((l>>4)&3)  (inverse of the XOR swizzle).
    const int c0 = wave * 2, c1 = wave * 2 + 1;
    const int sr0 = c0 * 16 + (lane >> 2);
    const int sr1 = c1 * 16 + (lane >> 2);
    const int sg  = (lane & 3) ^ ((lane >> 4) & 3);
    const u16* gA0 = zb + (size_t)(rowTile + sr0) * K_DIM + sg * 8;
    const u16* gA1 = zb + (size_t)(rowTile + sr1) * K_DIM + sg * 8;
    const u16* gB0 = eb + (size_t)(nTile + sr0) * K_DIM + sg * 8;
    const u16* gB1 = eb + (size_t)(nTile + sr1) * K_DIM + sg * 8;
    u16* lA0 = As + c0 * 512;  // 512 u16 = 1024B per chunk (wave-uniform)
    u16* lA1 = As + c1 * 512;
    u16* lB0 = Bs + c0 * 512;
    u16* lB1 = Bs + c1 * 512;

    // fragment read offsets (bytes), swizzled; lane: r=lane&15 (m/n), q=lane>>4 (k-group)
    int aoff[4], boff[4];
    #pragma unroll
    for (int t = 0; t < 4; t++) {
        int R = wm + t * 16 + (lane & 15);
        aoff[t] = (R * 4 + ((lane >> 4) ^ ((R >> 2) & 3))) * 16;
        int Rn = wn + t * 16 + (lane & 15);
        boff[t] = (Rn * 4 + ((lane >> 4) ^ ((Rn >> 2) & 3))) * 16;
    }

    f32x4 acc[4][4] = {};

    for (int kk = 0; kk < K_DIM; kk += BK) {
        ldg_to_lds16(gA0 + kk, lA0);
        ldg_to_lds16(gA1 + kk, lA1);
        ldg_to_lds16(gB0 + kk, lB0);
        ldg_to_lds16(gB1 + kk, lB1);
        __syncthreads();
        short8 af[4], bf_[4];
        #pragma unroll
        for (int t = 0; t < 4; t++) {
            af[t]  = *(const short8*)((const char*)As + aoff[t]);
            bf_[t] = *(const short8*)((const char*)Bs + boff[t]);
        }
        #pragma unroll
        for (int i = 0; i < 4; i++)
            #pragma unroll
            for (int j = 0; j < 4; j++)
                acc[i][j] = __builtin_amdgcn_mfma_f32_16x16x32_bf16(af[i], bf_[j], acc[i][j], 0, 0, 0);
        __syncthreads();
    }

    // ---- epilogue: s = en2 - 2*C ; per-row local min ; global running min ;
    //      candidate capture (admit if s <= runningMin + 2*tau) ----
    float e2v[4];
    #pragma unroll
    for (int j = 0; j < 4; j++) e2v[j] = en2s[wn + j * 16 + (lane & 15)];
    #pragma unroll
    for (int i = 0; i < 4; i++)
        #pragma unroll
        for (int j = 0; j < 4; j++)
            #pragma unroll
            for (int r = 0; r < 4; r++)
                acc[i][j][r] = e2v[j] - 2.0f * acc[i][j][r];

    float rm[4][4];
    #pragma unroll
    for (int i = 0; i < 4; i++)
        #pragma unroll
        for (int r = 0; r < 4; r++)
            rm[i][r] = fminf(fminf(acc[i][0][r], acc[i][1][r]),
                             fminf(acc[i][2][r], acc[i][3][r]));
    #pragma unroll
    for (int d = 1; d < 16; d <<= 1)
        #pragma unroll
        for (int i = 0; i < 4; i++)
            #pragma unroll
            for (int r = 0; r < 4; r++)
                rm[i][r] = fminf(rm[i][r], __shfl_xor(rm[i][r], d));

    if ((lane & 15) == 0) {
        #pragma unroll
        for (int i = 0; i < 4; i++)
            #pragma unroll
            for (int r = 0; r < 4; r++) {
                int lrow = wm + i * 16 + (lane >> 4) * 4 + r;
                u32 o = ford(rm[i][r]);
                atomicMin(&threshL[lrow], o);
                u32 old = atomicMin(&rowMin[rowTile + lrow], o);
                atomicMin(&threshL[lrow], old);
            }
    }
    __syncthreads();

    #pragma unroll
    for (int i = 0; i < 4; i++) {
        #pragma unroll
        for (int r = 0; r < 4; r++) {
            int lrow = wm + i * 16 + (lane >> 4) * 4 + r;
            float th = fordinv(threshL[lrow]) + TAU2;
            #pragma unroll
            for (int j = 0; j < 4; j++) {
                if (acc[i][j][r] <= th) {
                    u32 idx = atomicAdd(candCnt, 1u);
                    if (idx < CAND_CAP) {
                        u32 code = (u32)(nTile + wn + j * 16 + (lane & 15));
                        cand[idx] = ((u32)(rowTile + lrow) << 13) | code;
                    }
                }
            }
        }
    }
}

// ---------------- fp32 exact refine of candidates ----------------
// one wave per candidate: 64 lanes * 8 elems = 512-dot in fp32,
// packed (orderable dist, code) atomicMin -> ties pick lower code (np argmin).
__global__ void k_refine(const float* __restrict__ z, const float* __restrict__ emb,
                         const float* __restrict__ en2, const u32* __restrict__ candCnt,
                         const u32* __restrict__ cand, u64* __restrict__ rowBest) {
    u32 cnt = *candCnt; if (cnt > CAND_CAP) cnt = CAND_CAP;
    int gt = blockIdx.x * blockDim.x + threadIdx.x;
    u32 wid = (u32)(gt >> 6);
    int lane = gt & 63;
    u32 nw = (u32)((gridDim.x * blockDim.x) >> 6);
    for (u32 ci = wid; ci < cnt; ci += nw) {
        u32 rec = cand[ci];
        u32 row = rec >> 13, code = rec & (N_CODES - 1);
        const float4* zp = (const float4*)(z + (size_t)row * K_DIM) + lane * 2;
        const float4* ep = (const float4*)(emb + (size_t)code * K_DIM) + lane * 2;
        float4 a0 = zp[0], a1 = zp[1], b0 = ep[0], b1 = ep[1];
        float d = a0.x*b0.x + a0.y*b0.y + a0.z*b0.z + a0.w*b0.w
                + a1.x*b1.x + a1.y*b1.y + a1.z*b1.z + a1.w*b1.w;
        #pragma unroll
        for (int s = 32; s; s >>= 1) d += __shfl_xor(d, s);
        if (lane == 0) {
            float sv = en2[code] - 2.0f * d;
            u64 pk = ((u64)ford(sv) << 32) | (u64)code;
            atomicMin(rowBest + row, pk);
        }
    }
}

// ---------------- outputs: z_q gather, codes, counts ----------------
__global__ void k_output(const u64* __restrict__ rowBest, const float* __restrict__ emb,
                         float* __restrict__ out, u32* __restrict__ counts) {
    int row = blockIdx.x;
    u64 pk = rowBest[row];
    u32 code = (u32)(pk & 0xFFFFFFFFull);
    int t = threadIdx.x;  // 128 threads, 4 floats each
    float4 v = ((const float4*)(emb + (size_t)code * K_DIM))[t];
    ((float4*)(out + (size_t)row * K_DIM))[t] = v;
    if (t == 0) {
        out[OFF_CODES + row] = (float)code;
        atomicAdd(&counts[code], 1u);
    }
}

// ---------------- loss + perplexity ----------------
// loss = 0.25 * mean(||z - e_c||^2) ; per row ||z-e||^2 = zn2[row] + s_best[row]
__global__ void k_final(const u64* __restrict__ rowBest, const float* __restrict__ zn2,
                        const u32* __restrict__ counts, float* __restrict__ out) {
    __shared__ float red[256];
    int t = threadIdx.x;
    float s1 = 0.f;
    for (int r = t; r < M_ROWS; r += 256)
        s1 += zn2[r] + fordinv((u32)(rowBest[r] >> 32));
    red[t] = s1; __syncthreads();
    for (int w = 128; w; w >>= 1) { if (t < w) red[t] += red[t + w]; __syncthreads(); }
    float lossSum = red[0];
    __syncthreads();
    float s2 = 0.f;
    for (int c = t; c < N_CODES; c += 256) {
        float p = (float)counts[c] * (1.0f / (float)M_ROWS);
        s2 += p * logf(p + 1e-10f);
    }
    red[t] = s2; __syncthreads();
    for (int w = 128; w; w >>= 1) { if (t < w) red[t] += red[t + w]; __syncthreads(); }
    if (t == 0) {
        out[OFF_LOSS] = 0.25f * lossSum / ((float)M_ROWS * (float)K_DIM);
        out[OFF_PERP] = expf(-red[0]);
    }
}

// ---------------- workspace layout (bytes) ----------------
#define WS_ZB      ((size_t)0)                       // 32768*512*2  = 33554432
#define WS_EB      ((size_t)33554432)                // 8192*512*2   = 8388608
#define WS_EN2     ((size_t)41943040)                // 8192*4
#define WS_ZN2     ((size_t)41975808)                // 32768*4
#define WS_ROWMIN  ((size_t)42106880)                // 32768*4
#define WS_ROWBEST ((size_t)42237952)                // 32768*8
#define WS_COUNTS  ((size_t)42500096)                // 8192*4
#define WS_CANDCNT ((size_t)42532864)                // 256
#define WS_CAND    ((size_t)42533120)                // 4M*4 = 16777216 -> total ~59.3MB

extern "C" void kernel_launch(void* const* d_in, const int* in_sizes, int n_in,
                              void* d_out, int out_size, void* d_ws, size_t ws_size,
                              hipStream_t stream) {
    const float* z   = (const float*)d_in[0];
    const float* emb = (const float*)d_in[1];
    float* out = (float*)d_out;
    char* ws = (char*)d_ws;

    u16*  zb      = (u16*)(ws + WS_ZB);
    u16*  eb      = (u16*)(ws + WS_EB);
    float* en2    = (float*)(ws + WS_EN2);
    float* zn2    = (float*)(ws + WS_ZN2);
    u32*  rowMin  = (u32*)(ws + WS_ROWMIN);
    u64*  rowBest = (u64*)(ws + WS_ROWBEST);
    u32*  counts  = (u32*)(ws + WS_COUNTS);
    u32*  candCnt = (u32*)(ws + WS_CANDCNT);
    u32*  cand    = (u32*)(ws + WS_CAND);

    k_init<<<dim3(M_ROWS / 256), dim3(256), 0, stream>>>(rowMin, rowBest, counts, candCnt);
    k_convert<<<dim3(M_ROWS / 4), dim3(256), 0, stream>>>(z, zb, zn2, M_ROWS);
    k_convert<<<dim3(N_CODES / 4), dim3(256), 0, stream>>>(emb, eb, en2, N_CODES);
    k_gemm<<<dim3(M_ROWS / BM, N_CODES / BN), dim3(256), 0, stream>>>(zb, eb, en2, rowMin, candCnt, cand);
    k_refine<<<dim3(512), dim3(256), 0, stream>>>(z, emb, en2, candCnt, cand, rowBest);
    k_output<<<dim3(M_ROWS), dim3(128), 0, stream>>>(rowBest, emb, out, counts);
    k_final<<<dim3(1), dim3(256), 0, stream>>>(rowBest, zn2, counts, out);
}

// Round 2
// 640.778 us; speedup vs baseline: 3.4454x; 3.4454x over previous
//
#include <hip/hip_runtime.h>
#include <stdint.h>
#include <stddef.h>

// Problem constants (fixed by the reference)
#define M_ROWS 32768      // B*N = 16*2048
#define N_CODES 8192
#define K_DIM 512
#define BM 128
#define BN 128
#define BK 64
#define KITERS (K_DIM / BK)     // 8
#define CAND_CAP (3u*1024u*1024u)
#define LCAP 512u               // per-block LDS candidate slab
#define TAU2 2.0f               // 2*tau admission margin for bf16 approx distances (>10 sigma)

// Output layout (floats): z_q [0,16777216), codes [16777216,16809984), loss, perp
#define OFF_CODES 16777216
#define OFF_LOSS  (16777216 + 32768)
#define OFF_PERP  (16777216 + 32768 + 1)

using short8  = __attribute__((ext_vector_type(8))) short;
using ushort8 = __attribute__((ext_vector_type(8))) unsigned short;
using f32x4   = __attribute__((ext_vector_type(4))) float;

typedef unsigned short u16;
typedef unsigned int   u32;
typedef unsigned long long u64;

// ---- orderable-uint encoding of float (monotone: uint min == float min) ----
__device__ __forceinline__ u32 ford(float f) {
    u32 u = __float_as_uint(f);
    return (u & 0x80000000u) ? ~u : (u | 0x80000000u);
}
__device__ __forceinline__ float fordinv(u32 u) {
    u32 v = (u & 0x80000000u) ? (u & 0x7FFFFFFFu) : ~u;
    return __uint_as_float(v);
}
// fp32 -> bf16 (RNE)
__device__ __forceinline__ u16 f2bf(float f) {
    u32 u = __float_as_uint(f);
    u = u + 0x7FFFu + ((u >> 16) & 1u);
    return (u16)(u >> 16);
}

// async global->LDS, 16B per lane; LDS dest = wave-uniform base + lane*16
__device__ __forceinline__ void ldg_to_lds16(const u16* g, u16* l) {
    __builtin_amdgcn_global_load_lds((__attribute__((address_space(1))) void*)(g),
                                     (__attribute__((address_space(3))) void*)(l),
                                     16, 0, 0);
}

// ---------------- init scratch state ----------------
__global__ void k_init(u32* rowMin, u64* rowBest, u32* counts, u32* candCnt) {
    int i = blockIdx.x * blockDim.x + threadIdx.x;
    if (i < M_ROWS) { rowMin[i] = 0xFFFFFFFFu; rowBest[i] = ~0ull; }
    if (i < N_CODES) counts[i] = 0u;
    if (i == 0) *candCnt = 0u;
}

// ------------- fp32 -> bf16 convert + row squared norms -------------
__global__ void k_convert(const float* __restrict__ src, u16* __restrict__ dst,
                          float* __restrict__ nrm2, int nrows) {
    int row  = blockIdx.x * 4 + (threadIdx.x >> 6);
    int lane = threadIdx.x & 63;
    if (row >= nrows) return;
    const float* p = src + (size_t)row * K_DIM + lane * 8;
    float4 a = *(const float4*)p;
    float4 b = *(const float4*)(p + 4);
    ushort8 v;
    v[0]=f2bf(a.x); v[1]=f2bf(a.y); v[2]=f2bf(a.z); v[3]=f2bf(a.w);
    v[4]=f2bf(b.x); v[5]=f2bf(b.y); v[6]=f2bf(b.z); v[7]=f2bf(b.w);
    *(ushort8*)(dst + (size_t)row * K_DIM + lane * 8) = v;
    float ss = a.x*a.x + a.y*a.y + a.z*a.z + a.w*a.w
             + b.x*b.x + b.y*b.y + b.z*b.z + b.w*b.w;
    #pragma unroll
    for (int s = 32; s; s >>= 1) ss += __shfl_xor(ss, s);
    if (lane == 0) nrm2[row] = ss;
}

// ---------------- main bf16 GEMM + fused min/candidate epilogue ----------------
// s[m,n] = en2[n] - 2 * sum_k zb[m,k]*eb[n,k]  (row-wise argmin target)
// BK=64: row = 8 x 16B blocks; XOR swizzle: block (R,g) at slot R*8 + (g^(R&7))
// -> ds_read_b128 frag reads 2-way (free), global_load_lds stays lane-linear.
// Candidates aggregated in an LDS slab, ONE global atomicAdd per block.
__global__ __launch_bounds__(256, 4)
void k_gemm(const u16* __restrict__ zb, const u16* __restrict__ eb,
            const float* __restrict__ en2, u32* __restrict__ rowMin,
            u32* __restrict__ candCnt, u64* __restrict__ cand) {
    __shared__ __align__(16) u16 As[BM * BK];
    __shared__ __align__(16) u16 Bs[BN * BK];
    __shared__ float en2s[BN];
    __shared__ u32 threshL[BM];
    __shared__ u64 candBuf[LCAP];
    __shared__ u32 ldsCnt, ldsBase;

    const int tid  = threadIdx.x;
    const int lane = tid & 63;
    const int wave = tid >> 6;
    const int rowTile = blockIdx.x * BM;
    const int nTile   = blockIdx.y * BN;
    const int wm = (wave >> 1) * 64;   // wave's row quadrant
    const int wn = (wave & 1) * 64;    // wave's col quadrant

    if (tid < BN) { en2s[tid] = en2[nTile + tid]; threshL[tid] = 0xFFFFFFFFu; }
    if (tid == 0) ldsCnt = 0u;

    // staging: wave w handles wave-issues i = w*4+t (t=0..3) for A and for B.
    // issue i covers rows [i*8, i*8+8); lane l -> row i*8 + (l>>3),
    // k-block g = (l&7) ^ ((l>>3)&7)  (inverse of the XOR swizzle);
    // each 8-lane group covers one full 128B row segment (perfectly coalesced).
    const int srow = (lane >> 3);
    const int sg   = (lane & 7) ^ ((lane >> 3) & 7);
    const u16* gA[4]; const u16* gB[4]; u16* lA[4]; u16* lB[4];
    #pragma unroll
    for (int t = 0; t < 4; t++) {
        int i = wave * 4 + t;
        gA[t] = zb + (size_t)(rowTile + i * 8 + srow) * K_DIM + sg * 8;
        gB[t] = eb + (size_t)(nTile   + i * 8 + srow) * K_DIM + sg * 8;
        lA[t] = As + i * 512;   // 64 blocks * 8 u16 per wave-issue
        lB[t] = Bs + i * 512;
    }

    // fragment read byte offsets (slab 0); slab 1 = offset ^ 64
    int aoff[4], boff[4];
    const int q = lane >> 4;
    #pragma unroll
    for (int t = 0; t < 4; t++) {
        int R  = wm + t * 16 + (lane & 15);
        aoff[t] = (R * 8 + (q ^ (R & 7))) * 16;
        int Rn = wn + t * 16 + (lane & 15);
        boff[t] = (Rn * 8 + (q ^ (Rn & 7))) * 16;
    }

    f32x4 acc[4][4] = {};

    for (int kk = 0; kk < KITERS; kk++) {
        const int ko = kk * BK;
        #pragma unroll
        for (int t = 0; t < 4; t++) {
            ldg_to_lds16(gA[t] + ko, lA[t]);
            ldg_to_lds16(gB[t] + ko, lB[t]);
        }
        __syncthreads();
        short8 af[4], bf_[4];
        #pragma unroll
        for (int t = 0; t < 4; t++) {
            af[t]  = *(const short8*)((const char*)As + aoff[t]);
            bf_[t] = *(const short8*)((const char*)Bs + boff[t]);
        }
        #pragma unroll
        for (int i = 0; i < 4; i++)
            #pragma unroll
            for (int j = 0; j < 4; j++)
                acc[i][j] = __builtin_amdgcn_mfma_f32_16x16x32_bf16(af[i], bf_[j], acc[i][j], 0, 0, 0);
        #pragma unroll
        for (int t = 0; t < 4; t++) {
            af[t]  = *(const short8*)((const char*)As + (aoff[t] ^ 64));
            bf_[t] = *(const short8*)((const char*)Bs + (boff[t] ^ 64));
        }
        #pragma unroll
        for (int i = 0; i < 4; i++)
            #pragma unroll
            for (int j = 0; j < 4; j++)
                acc[i][j] = __builtin_amdgcn_mfma_f32_16x16x32_bf16(af[i], bf_[j], acc[i][j], 0, 0, 0);
        __syncthreads();
    }

    // ---- epilogue: s = en2 - 2*C ; per-row tile min ; candidate capture ----
    float e2v[4];
    #pragma unroll
    for (int j = 0; j < 4; j++) e2v[j] = en2s[wn + j * 16 + (lane & 15)];
    #pragma unroll
    for (int i = 0; i < 4; i++)
        #pragma unroll
        for (int j = 0; j < 4; j++)
            #pragma unroll
            for (int r = 0; r < 4; r++)
                acc[i][j][r] = e2v[j] - 2.0f * acc[i][j][r];

    float rm[4][4];
    #pragma unroll
    for (int i = 0; i < 4; i++)
        #pragma unroll
        for (int r = 0; r < 4; r++)
            rm[i][r] = fminf(fminf(acc[i][0][r], acc[i][1][r]),
                             fminf(acc[i][2][r], acc[i][3][r]));
    #pragma unroll
    for (int d = 1; d < 16; d <<= 1)
        #pragma unroll
        for (int i = 0; i < 4; i++)
            #pragma unroll
            for (int r = 0; r < 4; r++)
                rm[i][r] = fminf(rm[i][r], __shfl_xor(rm[i][r], d));

    if ((lane & 15) == 0) {
        #pragma unroll
        for (int i = 0; i < 4; i++)
            #pragma unroll
            for (int r = 0; r < 4; r++) {
                int lrow = wm + i * 16 + (lane >> 4) * 4 + r;
                u32 o = ford(rm[i][r]);
                atomicMin(&threshL[lrow], o);
                u32 old = atomicMin(&rowMin[rowTile + lrow], o);  // also tightens via earlier tiles
                atomicMin(&threshL[lrow], old);
            }
    }
    __syncthreads();

    #pragma unroll
    for (int i = 0; i < 4; i++) {
        #pragma unroll
        for (int r = 0; r < 4; r++) {
            int lrow = wm + i * 16 + (lane >> 4) * 4 + r;
            float th = fordinv(threshL[lrow]) + TAU2;
            #pragma unroll
            for (int j = 0; j < 4; j++) {
                float sv = acc[i][j][r];
                if (sv <= th) {
                    u32 code = (u32)(nTile + wn + j * 16 + (lane & 15));
                    u64 pk = ((u64)ford(sv) << 32) |
                             (u64)(((u32)(rowTile + lrow) << 13) | code);
                    u32 idx = atomicAdd(&ldsCnt, 1u);       // LDS atomic: cheap
                    if (idx < LCAP) candBuf[idx] = pk;
                    else { u32 g = atomicAdd(candCnt, 1u);  // rare overflow path
                           if (g < CAND_CAP) cand[g] = pk; }
                }
            }
        }
    }
    __syncthreads();
    if (tid == 0) {
        u32 n = ldsCnt < LCAP ? ldsCnt : LCAP;
        ldsBase = atomicAdd(candCnt, n);                    // ONE global atomic per block
    }
    __syncthreads();
    u32 n = ldsCnt < LCAP ? ldsCnt : LCAP;
    for (u32 k2 = tid; k2 < n; k2 += 256) {
        u32 g = ldsBase + k2;
        if (g < CAND_CAP) cand[g] = candBuf[k2];
    }
}

// ---------------- fp32 exact refine of pruned candidates ----------------
// prune vs completed global approx min (+2tau); survivors (~1/row) get an
// exact fp32 512-dot; packed (orderable dist, code) atomicMin -> np tie rule.
__global__ void k_refine(const float* __restrict__ z, const float* __restrict__ emb,
                         const float* __restrict__ en2, const u32* __restrict__ candCnt,
                         const u64* __restrict__ cand, const u32* __restrict__ rowMin,
                         u64* __restrict__ rowBest) {
    u32 cnt = *candCnt; if (cnt > CAND_CAP) cnt = CAND_CAP;
    int gt = blockIdx.x * blockDim.x + threadIdx.x;
    u32 wid = (u32)(gt >> 6);
    int lane = gt & 63;
    u32 nw = (u32)((gridDim.x * blockDim.x) >> 6);
    for (u32 ci = wid; ci < cnt; ci += nw) {
        u64 pk = cand[ci];
        u32 rc = (u32)pk;
        u32 row = rc >> 13, code = rc & (N_CODES - 1);
        float ad = fordinv((u32)(pk >> 32));
        float gm = fordinv(rowMin[row]);
        if (ad > gm + TAU2) continue;   // pruned: can't be the true argmin
        const float4* zp = (const float4*)(z + (size_t)row * K_DIM) + lane * 2;
        const float4* ep = (const float4*)(emb + (size_t)code * K_DIM) + lane * 2;
        float4 a0 = zp[0], a1 = zp[1], b0 = ep[0], b1 = ep[1];
        float d = a0.x*b0.x + a0.y*b0.y + a0.z*b0.z + a0.w*b0.w
                + a1.x*b1.x + a1.y*b1.y + a1.z*b1.z + a1.w*b1.w;
        #pragma unroll
        for (int s = 32; s; s >>= 1) d += __shfl_xor(d, s);
        if (lane == 0) {
            float sv = en2[code] - 2.0f * d;
            u64 bk = ((u64)ford(sv) << 32) | (u64)code;
            atomicMin(rowBest + row, bk);
        }
    }
}

// ---------------- outputs: z_q gather, codes, counts ----------------
__global__ void k_output(const u64* __restrict__ rowBest, const float* __restrict__ emb,
                         float* __restrict__ out, u32* __restrict__ counts) {
    int row = blockIdx.x;
    u64 pk = rowBest[row];
    u32 code = (u32)(pk & 0xFFFFFFFFull);
    int t = threadIdx.x;  // 128 threads, 4 floats each
    float4 v = ((const float4*)(emb + (size_t)code * K_DIM))[t];
    ((float4*)(out + (size_t)row * K_DIM))[t] = v;
    if (t == 0) {
        out[OFF_CODES + row] = (float)code;
        atomicAdd(&counts[code], 1u);
    }
}

// ---------------- loss + perplexity ----------------
__global__ void k_final(const u64* __restrict__ rowBest, const float* __restrict__ zn2,
                        const u32* __restrict__ counts, float* __restrict__ out) {
    __shared__ float red[256];
    int t = threadIdx.x;
    float s1 = 0.f;
    for (int r = t; r < M_ROWS; r += 256)
        s1 += zn2[r] + fordinv((u32)(rowBest[r] >> 32));
    red[t] = s1; __syncthreads();
    for (int w = 128; w; w >>= 1) { if (t < w) red[t] += red[t + w]; __syncthreads(); }
    float lossSum = red[0];
    __syncthreads();
    float s2 = 0.f;
    for (int c = t; c < N_CODES; c += 256) {
        float p = (float)counts[c] * (1.0f / (float)M_ROWS);
        s2 += p * logf(p + 1e-10f);
    }
    red[t] = s2; __syncthreads();
    for (int w = 128; w; w >>= 1) { if (t < w) red[t] += red[t + w]; __syncthreads(); }
    if (t == 0) {
        out[OFF_LOSS] = 0.25f * lossSum / ((float)M_ROWS * (float)K_DIM);
        out[OFF_PERP] = expf(-red[0]);
    }
}

// ---------------- workspace layout (bytes) ----------------
#define WS_ZB      ((size_t)0)                       // 32768*512*2  = 33554432
#define WS_EB      ((size_t)33554432)                // 8192*512*2   = 8388608
#define WS_EN2     ((size_t)41943040)                // 8192*4
#define WS_ZN2     ((size_t)41975808)                // 32768*4
#define WS_ROWMIN  ((size_t)42106880)                // 32768*4
#define WS_ROWBEST ((size_t)42237952)                // 32768*8
#define WS_COUNTS  ((size_t)42500096)                // 8192*4
#define WS_CANDCNT ((size_t)42532864)                // 256
#define WS_CAND    ((size_t)42533120)                // 3M*8 = 25165824 -> total ~67.7MB

extern "C" void kernel_launch(void* const* d_in, const int* in_sizes, int n_in,
                              void* d_out, int out_size, void* d_ws, size_t ws_size,
                              hipStream_t stream) {
    const float* z   = (const float*)d_in[0];
    const float* emb = (const float*)d_in[1];
    float* out = (float*)d_out;
    char* ws = (char*)d_ws;

    u16*  zb      = (u16*)(ws + WS_ZB);
    u16*  eb      = (u16*)(ws + WS_EB);
    float* en2    = (float*)(ws + WS_EN2);
    float* zn2    = (float*)(ws + WS_ZN2);
    u32*  rowMin  = (u32*)(ws + WS_ROWMIN);
    u64*  rowBest = (u64*)(ws + WS_ROWBEST);
    u32*  counts  = (u32*)(ws + WS_COUNTS);
    u32*  candCnt = (u32*)(ws + WS_CANDCNT);
    u64*  cand    = (u64*)(ws + WS_CAND);

    k_init<<<dim3(M_ROWS / 256), dim3(256), 0, stream>>>(rowMin, rowBest, counts, candCnt);
    k_convert<<<dim3(M_ROWS / 4), dim3(256), 0, stream>>>(z, zb, zn2, M_ROWS);
    k_convert<<<dim3(N_CODES / 4), dim3(256), 0, stream>>>(emb, eb, en2, N_CODES);
    k_gemm<<<dim3(M_ROWS / BM, N_CODES / BN), dim3(256), 0, stream>>>(zb, eb, en2, rowMin, candCnt, cand);
    k_refine<<<dim3(1024), dim3(256), 0, stream>>>(z, emb, en2, candCnt, cand, rowMin, rowBest);
    k_output<<<dim3(M_ROWS), dim3(128), 0, stream>>>(rowBest, emb, out, counts);
    k_final<<<dim3(1), dim3(256), 0, stream>>>(rowBest, zn2, counts, out);
}